// Round 14
// baseline (245.339 us; speedup 1.0000x reference)
//
#include <hip/hip_runtime.h>

static constexpr int B_   = 8;
static constexpr int C_   = 256;
static constexpr int CQK_ = 32;
static constexpr int N_   = 4096;   // 64*64

typedef __attribute__((ext_vector_type(4)))  float f32x4;
typedef __attribute__((ext_vector_type(16))) float f32x16;
typedef __attribute__((ext_vector_type(8)))  short short8;
typedef __attribute__((ext_vector_type(2)))  unsigned int u32x2;
typedef unsigned short ushort_t;

// round-to-nearest-even fp32 -> bf16
__device__ inline unsigned short f2bf(float f) {
    unsigned u = __float_as_uint(f);
    return (unsigned short)((u + 0x7FFFu + ((u >> 16) & 1u)) >> 16);
}
__device__ inline unsigned packbf(float lo, float hi) {
    return (unsigned)f2bf(lo) | ((unsigned)f2bf(hi) << 16);
}
// packed f32->bf16 pair, single VOP3 (validated r6+)
__device__ inline unsigned cvtpk(float lo, float hi) {
    unsigned r;
    asm("v_cvt_pk_bf16_f32 %0, %1, %2" : "=v"(r) : "v"(lo), "v"(hi));
    return r;
}
// raw transcendental exp2 (input = log2-domain; Q pre-scaled by log2e)
__device__ inline float vexp2(float x) {
    float r;
    asm("v_exp_f32 %0, %1" : "=v"(r) : "v"(x));
    return r;
}
// v_permlane32_swap_b32 (validated r10)
__device__ inline void plswap(unsigned& a, unsigned& b) {
    asm("v_permlane32_swap_b32 %0, %1" : "+v"(a), "+v"(b));
}

// proj x-tile swizzle (validated r3-r13)
__device__ inline int swzbits(int m) {
    return ((m & 3) << 5) | (((m >> 3) & 1) << 4);
}

template <int OFF>
__device__ inline u32x2 tr8(unsigned a) {
    u32x2 d;
    asm volatile("ds_read_b64_tr_b16 %0, %1 offset:%2"
                 : "=v"(d) : "v"(a), "i"(OFF));
    return d;
}

__device__ inline short8 mk8(u32x2 lo, u32x2 hi) {
    union { unsigned u[4]; short8 s; } v;
    v.u[0] = lo.x; v.u[1] = lo.y; v.u[2] = hi.x; v.u[3] = hi.y;
    return v.s;
}
__device__ inline short8 mk8u(unsigned a, unsigned b, unsigned c, unsigned d) {
    union { unsigned u[4]; short8 s; } v;
    v.u[0] = a; v.u[1] = b; v.u[2] = c; v.u[3] = d;
    return v.s;
}

// ---------------------------------------------------------------------------
// prep: weights -> bf16 (Wq pre-scaled by log2e), biases -> f32
// ---------------------------------------------------------------------------
__global__ __launch_bounds__(256) void prep_kernel(
    const float* __restrict__ Wq, const float* __restrict__ bq,
    const float* __restrict__ Wk, const float* __restrict__ bk,
    const float* __restrict__ Wv, const float* __restrict__ bv,
    ushort_t* __restrict__ Wall, float* __restrict__ ball)
{
    const int r = blockIdx.x;
    const int t = threadIdx.x;
    const float LOG2E = 1.4426950408889634f;
    const float* src;
    float bsrc, sc;
    if (r < 32)      { src = Wq + (size_t)r * C_;        bsrc = bq[r];      sc = LOG2E; }
    else if (r < 64) { src = Wk + (size_t)(r - 32) * C_; bsrc = bk[r - 32]; sc = 1.0f; }
    else             { src = Wv + (size_t)(r - 64) * C_; bsrc = bv[r - 64]; sc = 1.0f; }
    Wall[(size_t)r * C_ + t] = f2bf(src[t] * sc);
    if (t == 0) ball[r] = bsrc * sc;
}

// ---------------------------------------------------------------------------
// Projection via MFMA (r12/r13-validated, incl. the V quadrant image:
//   byte = ((b*64+chunk)*4 + 2*ch + mh)*8192 + (c&127)*64
//        + 16*(((m&31)>>3) ^ (c&3) ^ ((c>>2)&3)) + 2*(m&7) )
// grid = 512 blocks (b = blk&7, XCD-affine), 256 threads (4 waves)
// ---------------------------------------------------------------------------
__global__ __launch_bounds__(256) void proj_kernel(
    const float* __restrict__ x,
    const ushort_t* __restrict__ Wall, const float* __restrict__ ball,
    ushort_t* __restrict__ Qb, ushort_t* __restrict__ Kb, ushort_t* __restrict__ Vt)
{
    __shared__ __align__(16) unsigned char xs[C_ * 128];   // 32 KB: [c][64n] bf16
    typedef __attribute__((address_space(3))) unsigned char lds_byte;
    const unsigned sbase = (unsigned)(size_t)(lds_byte*)xs;

    const int b  = blockIdx.x & 7;
    const int n0 = (blockIdx.x >> 3) << 6;
    const int t  = threadIdx.x;

    {
        const int cst = t >> 4;
        const int n4  = (t & 15) << 2;
        const float* xb = x + (size_t)b * C_ * N_ + n0;
        #pragma unroll
        for (int i = 0; i < 16; ++i) {
            const int c = 16 * i + cst;
            float4 v = *(const float4*)(xb + (size_t)c * N_ + n4);
            u32x2 pk;
            pk.x = packbf(v.x, v.y);
            pk.y = packbf(v.z, v.w);
            *(u32x2*)(xs + c * 128 + ((n4 * 2) ^ swzbits(c))) = pk;
        }
    }
    __syncthreads();

    const int l  = t & 63, w = t >> 6;
    const int li = l & 15, g = l >> 4;
    const int rr = li >> 2, ss = l & 3;
    const int swz_tr = (rr << 5) | ((g & 1) << 4);

    f32x4 acc[5][4];
    #pragma unroll
    for (int i = 0; i < 5; ++i)
        #pragma unroll
        for (int j = 0; j < 4; ++j) acc[i][j] = (f32x4){0.f, 0.f, 0.f, 0.f};

    #pragma unroll 2
    for (int kg = 0; kg < 8; ++kg) {
        u32x2 pb[4][2];
        #pragma unroll
        for (int jn = 0; jn < 4; ++jn) {
            unsigned a = sbase + (32 * kg + 8 * g + rr) * 128
                       + ((32 * jn + 8 * ss) ^ swz_tr);
            pb[jn][0] = tr8<0>(a);
            pb[jn][1] = tr8<512>(a);
        }
        short8 af[5];
        #pragma unroll
        for (int tm = 0; tm < 5; ++tm)
            af[tm] = *(const short8*)(Wall + (size_t)(16 * (4 * tm + w) + li) * C_
                                      + 32 * kg + 8 * g);
        asm volatile("s_waitcnt lgkmcnt(0)" ::: "memory");
        __builtin_amdgcn_sched_barrier(0);
        #pragma unroll
        for (int jn = 0; jn < 4; ++jn) {
            short8 Bf = mk8(pb[jn][0], pb[jn][1]);
            acc[0][jn] = __builtin_amdgcn_mfma_f32_16x16x32_bf16(
                             af[0], Bf, acc[0][jn], 0, 0, 0);
            #pragma unroll
            for (int tm = 1; tm < 5; ++tm)
                acc[tm][jn] = __builtin_amdgcn_mfma_f32_16x16x32_bf16(
                                  Bf, af[tm], acc[tm][jn], 0, 0, 0);
        }
    }

    // ---- epilogue: Q/K (unchanged, validated) ----
    {
        const int oc0 = 16 * w + 4 * g;
        float4 bias = *(const float4*)(ball + oc0);
        ushort_t* dst = (w < 2) ? Qb : Kb;
        const int col = (w < 2) ? oc0 : (oc0 - 32);
        #pragma unroll
        for (int jn = 0; jn < 4; ++jn) {
            const int n = n0 + 16 * jn + li;
            f32x4 a = acc[0][jn];
            u32x2 pk;
            pk.x = packbf(a[0] + bias.x, a[1] + bias.y);
            pk.y = packbf(a[2] + bias.z, a[3] + bias.w);
            *(u32x2*)(dst + (size_t)(b * N_ + n) * CQK_ + col) = pk;
        }
    }
    // ---- epilogue: V quadrant image (validated r12) ----
    #pragma unroll
    for (int tm = 1; tm < 5; ++tm) {
        const int c  = 16 * (4 * tm + w) + li - 64;
        const float bc = ball[64 + c];
        const int ch = c >> 7;
        const int cl = c & 127;
        const int X  = (c & 3) ^ ((c >> 2) & 3);
        char* qbase = (char*)Vt + ((size_t)(b * 64 + (n0 >> 6)) * 4 + 2 * ch) * 8192
                    + cl * 64;
        #pragma unroll
        for (int jn = 0; jn < 4; ++jn) {
            const int mp = 16 * jn + 4 * g;
            const int mh = mp >> 5;
            const int jg = (mp & 31) >> 3;
            f32x4 a = acc[tm][jn];
            u32x2 pk;
            pk.x = packbf(a[0] + bc, a[1] + bc);
            pk.y = packbf(a[2] + bc, a[3] + bc);
            *(u32x2*)(qbase + mh * 8192 + 16 * (jg ^ X) + 8 * (g & 1)) = pk;
        }
    }
}

// ---------------------------------------------------------------------------
// Fused attention: c-half blocks for occupancy. grid = 1024 (b, n-tile, cb),
// block = 64q x 128c, 4 waves = (mh x ch2), wave = 32m x 64c, acc = 64 regs.
// Triple-buffered 4KB V DMA (depth-2 prefetch, vmcnt(12)); in-register P;
// barrier-free main loop; end combine over mh (2 syncthreads).
// LDS: 4 waves * 3 * 4KB + 1KB rstab = 50176 B. launch_bounds(256,3).
// ---------------------------------------------------------------------------
__global__ __launch_bounds__(256, 3) void attn_kernel(
    const float* __restrict__ x,
    const ushort_t* __restrict__ Qb, const ushort_t* __restrict__ Kb,
    const ushort_t* __restrict__ Vt,
    const float* __restrict__ gamma, float* __restrict__ out)
{
    __shared__ __align__(16) unsigned char smem[50176];

    const int blk = blockIdx.x;
    const int b   = blk & 7;
    const int nt  = (blk >> 3) & 63;
    const int cb  = blk >> 9;                  // c-half of 256: 0/1
    const int n0  = nt << 6;
    const int t   = threadIdx.x;
    const int l   = t & 63, w = t >> 6;
    const int l31 = l & 31, h2 = l >> 5;
    const int mh  = w & 1,  ch2 = w >> 1;      // wave: m-half x 64c-quarter
    const int sxv = ((l31 & 3) ^ ((l31 >> 2) & 3)) << 4;
    unsigned char* wlds = smem + w * 12288;    // 3 x 4 KB private V bufs
    float* rstab = (float*)(smem + 49152);

    // Q fragments (B-role: col = l31 -> q = n0+32jq+l31; k = 16kh+8h2+j)
    short8 qfv[2][2];
    #pragma unroll
    for (int jq = 0; jq < 2; ++jq)
        #pragma unroll
        for (int kh = 0; kh < 2; ++kh)
            qfv[jq][kh] = *(const short8*)(Qb
                + (size_t)(b * N_ + n0 + 32 * jq + l31) * CQK_ + 16 * kh + 8 * h2);

    f32x16 acc[2][2];
    #pragma unroll
    for (int i = 0; i < 2; ++i)
        #pragma unroll
        for (int j = 0; j < 2; ++j)
            #pragma unroll
            for (int e = 0; e < 16; ++e) acc[i][j][e] = 0.f;
    f32x16 zf16;
    #pragma unroll
    for (int e = 0; e < 16; ++e) zf16[e] = 0.f;
    float rs[2] = {0.f, 0.f};

    const ushort_t* Kbb = Kb + (size_t)(b * N_) * CQK_;
    const char* Vgb = (const char*)Vt + (size_t)b * 64 * 32768
                    + (2 * cb + mh) * 8192 + ch2 * 4096;   // my 4KB granule

    short8 kfA[2], kfB[2];
    int vcur = 0;

// QK for one jq of the chunk using K-set KQ; exp2; pack+permlane -> PAW
#define QK_JQ(JQ, KQ, PAW)                                                      \
    {                                                                           \
        f32x16 sv = __builtin_amdgcn_mfma_f32_32x32x16_bf16(                    \
                        KQ[0], qfv[JQ][0], zf16, 0, 0, 0);                      \
        sv = __builtin_amdgcn_mfma_f32_32x32x16_bf16(                           \
                 KQ[1], qfv[JQ][1], sv, 0, 0, 0);                               \
        _Pragma("unroll")                                                       \
        for (int s = 0; s < 2; ++s) {                                           \
            float e0 = vexp2(sv[8*s+0]), e1 = vexp2(sv[8*s+1]);                 \
            float e2 = vexp2(sv[8*s+2]), e3 = vexp2(sv[8*s+3]);                 \
            float e4 = vexp2(sv[8*s+4]), e5 = vexp2(sv[8*s+5]);                 \
            float e6 = vexp2(sv[8*s+6]), e7 = vexp2(sv[8*s+7]);                 \
            rs[JQ] += ((e0 + e1) + (e2 + e3)) + ((e4 + e5) + (e6 + e7));        \
            unsigned u0 = cvtpk(e0, e1), u1 = cvtpk(e2, e3);                    \
            unsigned u2 = cvtpk(e4, e5), u3 = cvtpk(e6, e7);                    \
            plswap(u0, u2); plswap(u1, u3);                                     \
            PAW[JQ][s][0] = u0; PAW[JQ][s][1] = u1;                             \
            PAW[JQ][s][2] = u2; PAW[JQ][s][3] = u3;                             \
        }                                                                       \
    }

#define BODY(N, KC)                                                             \
    {                                                                           \
        const int chd = ((N) + 2) & 63;                                         \
        /* 1. DMA(n+2) my 4KB granule -> buf[(n+2)%3] */                        \
        int vnext = vcur + 2; if (vnext >= 3) vnext -= 3;                       \
        {                                                                       \
            const char* gsrc = Vgb + (size_t)chd * 32768 + l * 16;              \
            unsigned char* ldst = wlds + vnext * 4096 + l * 16;                 \
            _Pragma("unroll")                                                   \
            for (int i = 0; i < 4; ++i)                                         \
                __builtin_amdgcn_global_load_lds(                               \
                    (const __attribute__((address_space(1))) unsigned int*)(gsrc + i * 1024), \
                    (__attribute__((address_space(3))) unsigned int*)(ldst + i * 1024), \
                    16, 0, 0);                                                  \
        }                                                                       \
        /* 2. QK(n) own 32-m half -> register P */                              \
        unsigned paw[2][2][4];                                                  \
        QK_JQ(0, KC, paw)                                                       \
        QK_JQ(1, KC, paw)                                                       \
        /* 3. K(n+2) -> same regs (freed by QK) */                              \
        _Pragma("unroll")                                                       \
        for (int kh = 0; kh < 2; ++kh)                                          \
            KC[kh] = *(const short8*)(Kbb                                       \
                + (size_t)(64 * chd + 32 * mh + l31) * CQK_ + 16 * kh + 8 * h2);\
        /* 4. retire DMA(n); keep DMA(n+1,n+2)=8 + K=4 in flight */             \
        asm volatile("s_waitcnt vmcnt(12)" ::: "memory");                       \
        /* 5. PV(n): A = register P, B = V b128 (own 64c) */                    \
        {                                                                       \
            const unsigned char* vb = wlds + vcur * 4096;                       \
            _Pragma("unroll")                                                   \
            for (int s = 0; s < 2; ++s) {                                       \
                short8 A0 = mk8u(paw[0][s][0], paw[0][s][1],                    \
                                 paw[0][s][2], paw[0][s][3]);                   \
                short8 A1 = mk8u(paw[1][s][0], paw[1][s][1],                    \
                                 paw[1][s][2], paw[1][s][3]);                   \
                _Pragma("unroll")                                               \
                for (int jc = 0; jc < 2; ++jc) {                                \
                    short8 vv = *(const short8*)(vb + (32 * jc + l31) * 64      \
                                   + ((32 * s + 16 * h2) ^ sxv));               \
                    acc[0][jc] = __builtin_amdgcn_mfma_f32_32x32x16_bf16(       \
                                     A0, vv, acc[0][jc], 0, 0, 0);              \
                    acc[1][jc] = __builtin_amdgcn_mfma_f32_32x32x16_bf16(       \
                                     A1, vv, acc[1][jc], 0, 0, 0);              \
                }                                                               \
            }                                                                   \
        }                                                                       \
        vcur = (vcur == 2) ? 0 : vcur + 1;                                      \
    }

    // ---- prologue: K(0)->kfA, K(1)->kfB, DMA(0)->buf0, DMA(1)->buf1 ----
    #pragma unroll
    for (int kh = 0; kh < 2; ++kh) {
        kfA[kh] = *(const short8*)(Kbb + (size_t)(32 * mh + l31) * CQK_
                                   + 16 * kh + 8 * h2);
        kfB[kh] = *(const short8*)(Kbb + (size_t)(64 + 32 * mh + l31) * CQK_
                                   + 16 * kh + 8 * h2);
    }
    #pragma unroll
    for (int i = 0; i < 4; ++i) {
        __builtin_amdgcn_global_load_lds(
            (const __attribute__((address_space(1))) unsigned int*)(Vgb + l * 16 + i * 1024),
            (__attribute__((address_space(3))) unsigned int*)(wlds + l * 16 + i * 1024),
            16, 0, 0);
        __builtin_amdgcn_global_load_lds(
            (const __attribute__((address_space(1))) unsigned int*)(Vgb + 32768 + l * 16 + i * 1024),
            (__attribute__((address_space(3))) unsigned int*)(wlds + 4096 + l * 16 + i * 1024),
            16, 0, 0);
    }

    for (int mc = 0; mc < 62; mc += 2) {
        BODY(mc,     kfA)
        BODY(mc + 1, kfB)
    }
    BODY(62, kfA)

    // ---- tail: QK(63) + PV(63) ----
    {
        unsigned paw[2][2][4];
        QK_JQ(0, kfB, paw)
        QK_JQ(1, kfB, paw)
        asm volatile("s_waitcnt vmcnt(0)" ::: "memory");
        const unsigned char* vb = wlds + vcur * 4096;   // 63 % 3 == 0 -> vcur
        #pragma unroll
        for (int s = 0; s < 2; ++s) {
            short8 A0 = mk8u(paw[0][s][0], paw[0][s][1], paw[0][s][2], paw[0][s][3]);
            short8 A1 = mk8u(paw[1][s][0], paw[1][s][1], paw[1][s][2], paw[1][s][3]);
            #pragma unroll
            for (int jc = 0; jc < 2; ++jc) {
                short8 vv = *(const short8*)(vb + (32 * jc + l31) * 64
                               + ((32 * s + 16 * h2) ^ sxv));
                acc[0][jc] = __builtin_amdgcn_mfma_f32_32x32x16_bf16(
                                 A0, vv, acc[0][jc], 0, 0, 0);
                acc[1][jc] = __builtin_amdgcn_mfma_f32_32x32x16_bf16(
                                 A1, vv, acc[1][jc], 0, 0, 0);
            }
        }
    }
#undef BODY
#undef QK_JQ

    // ---- partial rowsums (own m-half): combine h2 halves, publish ----
    #pragma unroll
    for (int jq = 0; jq < 2; ++jq)
        rs[jq] += __shfl_xor(rs[jq], 32, 64);
    if (l < 32) {
        rstab[(w * 2 + 0) * 32 + l31] = rs[0];
        rstab[(w * 2 + 1) * 32 + l31] = rs[1];
    }
    __syncthreads();

    // ---- odd waves (mh=1): write partial acc into V-buffer area ----
    if (mh == 1) {
        float* dst = (float*)(smem + ch2 * 16384);
        #pragma unroll
        for (int jq = 0; jq < 2; ++jq)
            #pragma unroll
            for (int jc = 0; jc < 2; ++jc) {
                float* tb = dst + (jq * 2 + jc) * 1024 + l * 16;
                #pragma unroll
                for (int e4 = 0; e4 < 4; ++e4) {
                    f32x4 p;
                    p[0] = acc[jq][jc][4 * e4 + 0];
                    p[1] = acc[jq][jc][4 * e4 + 1];
                    p[2] = acc[jq][jc][4 * e4 + 2];
                    p[3] = acc[jq][jc][4 * e4 + 3];
                    *(f32x4*)(tb + 4 * (e4 ^ (l & 3))) = p;
                }
            }
    }
    __syncthreads();

    // ---- even waves (mh=0): combine + normalize + residual + store ----
    if (mh == 0) {
        const float* src = (const float*)(smem + ch2 * 16384);
        #pragma unroll
        for (int jq = 0; jq < 2; ++jq)
            #pragma unroll
            for (int jc = 0; jc < 2; ++jc) {
                const float* tb = src + (jq * 2 + jc) * 1024 + l * 16;
                #pragma unroll
                for (int e4 = 0; e4 < 4; ++e4) {
                    f32x4 p = *(const f32x4*)(tb + 4 * (e4 ^ (l & 3)));
                    acc[jq][jc][4 * e4 + 0] += p[0];
                    acc[jq][jc][4 * e4 + 1] += p[1];
                    acc[jq][jc][4 * e4 + 2] += p[2];
                    acc[jq][jc][4 * e4 + 3] += p[3];
                }
            }
        const float gm = gamma[0];
        #pragma unroll
        for (int jq = 0; jq < 2; ++jq)
            #pragma unroll
            for (int rg = 0; rg < 4; ++rg) {
                f32x4 s0 = *(const f32x4*)(rstab + (w * 2 + jq) * 32
                                           + 8 * rg + 4 * h2);
                f32x4 s1 = *(const f32x4*)(rstab + ((w + 1) * 2 + jq) * 32
                                           + 8 * rg + 4 * h2);
                float i0 = 1.0f / (s0[0] + s1[0]);
                float i1 = 1.0f / (s0[1] + s1[1]);
                float i2 = 1.0f / (s0[2] + s1[2]);
                float i3 = 1.0f / (s0[3] + s1[3]);
                const int n = n0 + 32 * jq + 8 * rg + 4 * h2;
                #pragma unroll
                for (int jc = 0; jc < 2; ++jc) {
                    const int c = 128 * cb + 64 * ch2 + 32 * jc + l31;
                    const size_t rowoff = (size_t)(b * C_ + c) * N_ + n;
                    float4 xv = *(const float4*)(x + rowoff);
                    float4 o;
                    o.x = gm * acc[jq][jc][4 * rg + 0] * i0 + xv.x;
                    o.y = gm * acc[jq][jc][4 * rg + 1] * i1 + xv.y;
                    o.z = gm * acc[jq][jc][4 * rg + 2] * i2 + xv.z;
                    o.w = gm * acc[jq][jc][4 * rg + 3] * i3 + xv.w;
                    *(float4*)(out + rowoff) = o;
                }
            }
    }
}

// ---------------------------------------------------------------------------
extern "C" void kernel_launch(void* const* d_in, const int* in_sizes, int n_in,
                              void* d_out, int out_size, void* d_ws, size_t ws_size,
                              hipStream_t stream)
{
    const float* x     = (const float*)d_in[0];
    const float* Wq    = (const float*)d_in[1];
    const float* bq    = (const float*)d_in[2];
    const float* Wk    = (const float*)d_in[3];
    const float* bk    = (const float*)d_in[4];
    const float* Wv    = (const float*)d_in[5];
    const float* bv    = (const float*)d_in[6];
    const float* gamma = (const float*)d_in[7];
    float* out = (float*)d_out;

    ushort_t* ws = (ushort_t*)d_ws;
    ushort_t* Qb   = ws;                                  // B*N*32 bf16
    ushort_t* Kb   = Qb + (size_t)B_ * N_ * CQK_;         // B*N*32 bf16
    ushort_t* Vt   = Kb + (size_t)B_ * N_ * CQK_;         // B*64 chunks * 32KB
    ushort_t* Wall = Vt + (size_t)B_ * C_ * N_;           // 320*256 bf16
    float*    ball = (float*)(Wall + (size_t)320 * C_);   // 320 f32

    prep_kernel<<<320, 256, 0, stream>>>(Wq, bq, Wk, bk, Wv, bv, Wall, ball);
    proj_kernel<<<B_ * (N_ / 64), 256, 0, stream>>>(x, Wall, ball, Qb, Kb, Vt);
    attn_kernel<<<B_ * (N_ / 64) * 2, 256, 0, stream>>>(x, Qb, Kb, Vt, gamma, out);
}

// Round 15
// 170.980 us; speedup vs baseline: 1.4349x; 1.4349x over previous
//
#include <hip/hip_runtime.h>

static constexpr int B_   = 8;
static constexpr int C_   = 256;
static constexpr int CQK_ = 32;
static constexpr int N_   = 4096;   // 64*64

typedef __attribute__((ext_vector_type(4)))  float f32x4;
typedef __attribute__((ext_vector_type(16))) float f32x16;
typedef __attribute__((ext_vector_type(8)))  short short8;
typedef __attribute__((ext_vector_type(2)))  unsigned int u32x2;
typedef unsigned short ushort_t;

// round-to-nearest-even fp32 -> bf16
__device__ inline unsigned short f2bf(float f) {
    unsigned u = __float_as_uint(f);
    return (unsigned short)((u + 0x7FFFu + ((u >> 16) & 1u)) >> 16);
}
__device__ inline unsigned packbf(float lo, float hi) {
    return (unsigned)f2bf(lo) | ((unsigned)f2bf(hi) << 16);
}
// packed f32->bf16 pair, single VOP3 (validated r6+)
__device__ inline unsigned cvtpk(float lo, float hi) {
    unsigned r;
    asm("v_cvt_pk_bf16_f32 %0, %1, %2" : "=v"(r) : "v"(lo), "v"(hi));
    return r;
}
// raw transcendental exp2 (input = log2-domain; Q pre-scaled by log2e)
__device__ inline float vexp2(float x) {
    float r;
    asm("v_exp_f32 %0, %1" : "=v"(r) : "v"(x));
    return r;
}
// v_permlane32_swap_b32 (validated r10)
__device__ inline void plswap(unsigned& a, unsigned& b) {
    asm("v_permlane32_swap_b32 %0, %1" : "+v"(a), "+v"(b));
}

// proj x-tile swizzle (validated r3-r14)
__device__ inline int swzbits(int m) {
    return ((m & 3) << 5) | (((m >> 3) & 1) << 4);
}

template <int OFF>
__device__ inline u32x2 tr8(unsigned a) {
    u32x2 d;
    asm volatile("ds_read_b64_tr_b16 %0, %1 offset:%2"
                 : "=v"(d) : "v"(a), "i"(OFF));
    return d;
}

__device__ inline short8 mk8(u32x2 lo, u32x2 hi) {
    union { unsigned u[4]; short8 s; } v;
    v.u[0] = lo.x; v.u[1] = lo.y; v.u[2] = hi.x; v.u[3] = hi.y;
    return v.s;
}
__device__ inline short8 mk8u(unsigned a, unsigned b, unsigned c, unsigned d) {
    union { unsigned u[4]; short8 s; } v;
    v.u[0] = a; v.u[1] = b; v.u[2] = c; v.u[3] = d;
    return v.s;
}

// ---------------------------------------------------------------------------
// prep: weights -> bf16 (Wq pre-scaled by log2e), biases -> f32
// ---------------------------------------------------------------------------
__global__ __launch_bounds__(256) void prep_kernel(
    const float* __restrict__ Wq, const float* __restrict__ bq,
    const float* __restrict__ Wk, const float* __restrict__ bk,
    const float* __restrict__ Wv, const float* __restrict__ bv,
    ushort_t* __restrict__ Wall, float* __restrict__ ball)
{
    const int r = blockIdx.x;
    const int t = threadIdx.x;
    const float LOG2E = 1.4426950408889634f;
    const float* src;
    float bsrc, sc;
    if (r < 32)      { src = Wq + (size_t)r * C_;        bsrc = bq[r];      sc = LOG2E; }
    else if (r < 64) { src = Wk + (size_t)(r - 32) * C_; bsrc = bk[r - 32]; sc = 1.0f; }
    else             { src = Wv + (size_t)(r - 64) * C_; bsrc = bv[r - 64]; sc = 1.0f; }
    Wall[(size_t)r * C_ + t] = f2bf(src[t] * sc);
    if (t == 0) ball[r] = bsrc * sc;
}

// ---------------------------------------------------------------------------
// Projection via MFMA (r12-r14 validated, incl. the V quadrant image:
//   byte = ((b*64+chunk)*4 + 2*ch + mh)*8192 + (c&127)*64
//        + 16*(((m&31)>>3) ^ (c&3) ^ ((c>>2)&3)) + 2*(m&7) )
// grid = 512 blocks (b = blk&7, XCD-affine), 256 threads (4 waves)
// ---------------------------------------------------------------------------
__global__ __launch_bounds__(256) void proj_kernel(
    const float* __restrict__ x,
    const ushort_t* __restrict__ Wall, const float* __restrict__ ball,
    ushort_t* __restrict__ Qb, ushort_t* __restrict__ Kb, ushort_t* __restrict__ Vt)
{
    __shared__ __align__(16) unsigned char xs[C_ * 128];   // 32 KB: [c][64n] bf16
    typedef __attribute__((address_space(3))) unsigned char lds_byte;
    const unsigned sbase = (unsigned)(size_t)(lds_byte*)xs;

    const int b  = blockIdx.x & 7;
    const int n0 = (blockIdx.x >> 3) << 6;
    const int t  = threadIdx.x;

    {
        const int cst = t >> 4;
        const int n4  = (t & 15) << 2;
        const float* xb = x + (size_t)b * C_ * N_ + n0;
        #pragma unroll
        for (int i = 0; i < 16; ++i) {
            const int c = 16 * i + cst;
            float4 v = *(const float4*)(xb + (size_t)c * N_ + n4);
            u32x2 pk;
            pk.x = packbf(v.x, v.y);
            pk.y = packbf(v.z, v.w);
            *(u32x2*)(xs + c * 128 + ((n4 * 2) ^ swzbits(c))) = pk;
        }
    }
    __syncthreads();

    const int l  = t & 63, w = t >> 6;
    const int li = l & 15, g = l >> 4;
    const int rr = li >> 2, ss = l & 3;
    const int swz_tr = (rr << 5) | ((g & 1) << 4);

    f32x4 acc[5][4];
    #pragma unroll
    for (int i = 0; i < 5; ++i)
        #pragma unroll
        for (int j = 0; j < 4; ++j) acc[i][j] = (f32x4){0.f, 0.f, 0.f, 0.f};

    #pragma unroll 2
    for (int kg = 0; kg < 8; ++kg) {
        u32x2 pb[4][2];
        #pragma unroll
        for (int jn = 0; jn < 4; ++jn) {
            unsigned a = sbase + (32 * kg + 8 * g + rr) * 128
                       + ((32 * jn + 8 * ss) ^ swz_tr);
            pb[jn][0] = tr8<0>(a);
            pb[jn][1] = tr8<512>(a);
        }
        short8 af[5];
        #pragma unroll
        for (int tm = 0; tm < 5; ++tm)
            af[tm] = *(const short8*)(Wall + (size_t)(16 * (4 * tm + w) + li) * C_
                                      + 32 * kg + 8 * g);
        asm volatile("s_waitcnt lgkmcnt(0)" ::: "memory");
        __builtin_amdgcn_sched_barrier(0);
        #pragma unroll
        for (int jn = 0; jn < 4; ++jn) {
            short8 Bf = mk8(pb[jn][0], pb[jn][1]);
            acc[0][jn] = __builtin_amdgcn_mfma_f32_16x16x32_bf16(
                             af[0], Bf, acc[0][jn], 0, 0, 0);
            #pragma unroll
            for (int tm = 1; tm < 5; ++tm)
                acc[tm][jn] = __builtin_amdgcn_mfma_f32_16x16x32_bf16(
                                  Bf, af[tm], acc[tm][jn], 0, 0, 0);
        }
    }

    // ---- epilogue: Q/K (unchanged, validated) ----
    {
        const int oc0 = 16 * w + 4 * g;
        float4 bias = *(const float4*)(ball + oc0);
        ushort_t* dst = (w < 2) ? Qb : Kb;
        const int col = (w < 2) ? oc0 : (oc0 - 32);
        #pragma unroll
        for (int jn = 0; jn < 4; ++jn) {
            const int n = n0 + 16 * jn + li;
            f32x4 a = acc[0][jn];
            u32x2 pk;
            pk.x = packbf(a[0] + bias.x, a[1] + bias.y);
            pk.y = packbf(a[2] + bias.z, a[3] + bias.w);
            *(u32x2*)(dst + (size_t)(b * N_ + n) * CQK_ + col) = pk;
        }
    }
    // ---- epilogue: V quadrant image (validated r12-r14) ----
    #pragma unroll
    for (int tm = 1; tm < 5; ++tm) {
        const int c  = 16 * (4 * tm + w) + li - 64;
        const float bc = ball[64 + c];
        const int ch = c >> 7;
        const int cl = c & 127;
        const int X  = (c & 3) ^ ((c >> 2) & 3);
        char* qbase = (char*)Vt + ((size_t)(b * 64 + (n0 >> 6)) * 4 + 2 * ch) * 8192
                    + cl * 64;
        #pragma unroll
        for (int jn = 0; jn < 4; ++jn) {
            const int mp = 16 * jn + 4 * g;
            const int mh = mp >> 5;
            const int jg = (mp & 31) >> 3;
            f32x4 a = acc[tm][jn];
            u32x2 pk;
            pk.x = packbf(a[0] + bc, a[1] + bc);
            pk.y = packbf(a[2] + bc, a[3] + bc);
            *(u32x2*)(qbase + mh * 8192 + 16 * (jg ^ X) + 8 * (g & 1)) = pk;
        }
    }
}

// ---------------------------------------------------------------------------
// Fused attention: c-half blocks (r14 geometry, validated), register-lean.
// grid = 1024 (b, n-tile, cb), block = 64q x 128c, 4 waves = (mh x ch2),
// wave = 32m x 64c, acc = 64 regs. Double-buffered 4KB V DMA, single-K
// prefetch, in-register P, barrier-free loop, end combine over mh.
// LDS: 4 waves * 2 * 4KB + 1KB rstab = 33792 B. NO register cap (r14 spilled).
// ---------------------------------------------------------------------------
__global__ __launch_bounds__(256) void attn_kernel(
    const float* __restrict__ x,
    const ushort_t* __restrict__ Qb, const ushort_t* __restrict__ Kb,
    const ushort_t* __restrict__ Vt,
    const float* __restrict__ gamma, float* __restrict__ out)
{
    __shared__ __align__(16) unsigned char smem[33792];

    const int blk = blockIdx.x;
    const int b   = blk & 7;
    const int nt  = (blk >> 3) & 63;
    const int cb  = blk >> 9;                  // c-half of 256: 0/1
    const int n0  = nt << 6;
    const int t   = threadIdx.x;
    const int l   = t & 63, w = t >> 6;
    const int l31 = l & 31, h2 = l >> 5;
    const int mh  = w & 1,  ch2 = w >> 1;      // wave: m-half x 64c-quarter
    const int sxv = ((l31 & 3) ^ ((l31 >> 2) & 3)) << 4;
    unsigned char* wlds = smem + w * 8192;     // 2 x 4 KB private V bufs
    float* rstab = (float*)(smem + 32768);

    // Q fragments (B-role: col = l31 -> q = n0+32jq+l31; k = 16kh+8h2+j)
    short8 qfv[2][2];
    #pragma unroll
    for (int jq = 0; jq < 2; ++jq)
        #pragma unroll
        for (int kh = 0; kh < 2; ++kh)
            qfv[jq][kh] = *(const short8*)(Qb
                + (size_t)(b * N_ + n0 + 32 * jq + l31) * CQK_ + 16 * kh + 8 * h2);

    f32x16 acc[2][2];
    #pragma unroll
    for (int i = 0; i < 2; ++i)
        #pragma unroll
        for (int j = 0; j < 2; ++j)
            #pragma unroll
            for (int e = 0; e < 16; ++e) acc[i][j][e] = 0.f;
    f32x16 zf16;
    #pragma unroll
    for (int e = 0; e < 16; ++e) zf16[e] = 0.f;
    float rs[2] = {0.f, 0.f};

    const ushort_t* Kbb = Kb + (size_t)(b * N_) * CQK_;
    const char* Vgb = (const char*)Vt + (size_t)b * 64 * 32768
                    + (2 * cb + mh) * 8192 + ch2 * 4096;   // my 4KB granule

    short8 kf[2];

// QK for one jq of the chunk using kf; exp2; pack+permlane -> PAW
#define QK_JQ(JQ, PAW)                                                          \
    {                                                                           \
        f32x16 sv = __builtin_amdgcn_mfma_f32_32x32x16_bf16(                    \
                        kf[0], qfv[JQ][0], zf16, 0, 0, 0);                      \
        sv = __builtin_amdgcn_mfma_f32_32x32x16_bf16(                           \
                 kf[1], qfv[JQ][1], sv, 0, 0, 0);                               \
        _Pragma("unroll")                                                       \
        for (int s = 0; s < 2; ++s) {                                           \
            float e0 = vexp2(sv[8*s+0]), e1 = vexp2(sv[8*s+1]);                 \
            float e2 = vexp2(sv[8*s+2]), e3 = vexp2(sv[8*s+3]);                 \
            float e4 = vexp2(sv[8*s+4]), e5 = vexp2(sv[8*s+5]);                 \
            float e6 = vexp2(sv[8*s+6]), e7 = vexp2(sv[8*s+7]);                 \
            rs[JQ] += ((e0 + e1) + (e2 + e3)) + ((e4 + e5) + (e6 + e7));        \
            unsigned u0 = cvtpk(e0, e1), u1 = cvtpk(e2, e3);                    \
            unsigned u2 = cvtpk(e4, e5), u3 = cvtpk(e6, e7);                    \
            plswap(u0, u2); plswap(u1, u3);                                     \
            PAW[JQ][s][0] = u0; PAW[JQ][s][1] = u1;                             \
            PAW[JQ][s][2] = u2; PAW[JQ][s][3] = u3;                             \
        }                                                                       \
    }

#define BODY(N, BOFF)                                                           \
    {                                                                           \
        /* 1. QK(n) own 32-m half -> register P (implicit kf wait drains */     \
        /*    DMA(n) too: vmcnt is in-order and DMA(n) is older than kf) */     \
        unsigned paw[2][2][4];                                                  \
        QK_JQ(0, paw)                                                           \
        QK_JQ(1, paw)                                                           \
        /* 2. K(n+1) -> kf (regs just freed by QK) */                           \
        {                                                                       \
            const int chk = ((N) + 1) & 63;                                     \
            _Pragma("unroll")                                                   \
            for (int kh = 0; kh < 2; ++kh)                                      \
                kf[kh] = *(const short8*)(Kbb                                   \
                    + (size_t)(64 * chk + 32 * mh + l31) * CQK_                 \
                    + 16 * kh + 8 * h2);                                        \
        }                                                                       \
        /* 3. belt: DMA(n) retired; K(n+1)=2 + DMA(n+1)=4 stay in flight */     \
        asm volatile("s_waitcnt vmcnt(6)" ::: "memory");                        \
        /* 4. PV(n): A = register P, B = V b128 (own 64c granule) */            \
        __builtin_amdgcn_s_setprio(1);                                          \
        {                                                                       \
            const unsigned char* vb = wlds + (BOFF);                            \
            _Pragma("unroll")                                                   \
            for (int s = 0; s < 2; ++s) {                                       \
                short8 A0 = mk8u(paw[0][s][0], paw[0][s][1],                    \
                                 paw[0][s][2], paw[0][s][3]);                   \
                short8 A1 = mk8u(paw[1][s][0], paw[1][s][1],                    \
                                 paw[1][s][2], paw[1][s][3]);                   \
                _Pragma("unroll")                                               \
                for (int jc = 0; jc < 2; ++jc) {                                \
                    short8 vv = *(const short8*)(vb + (32 * jc + l31) * 64      \
                                   + ((32 * s + 16 * h2) ^ sxv));               \
                    acc[0][jc] = __builtin_amdgcn_mfma_f32_32x32x16_bf16(       \
                                     A0, vv, acc[0][jc], 0, 0, 0);              \
                    acc[1][jc] = __builtin_amdgcn_mfma_f32_32x32x16_bf16(       \
                                     A1, vv, acc[1][jc], 0, 0, 0);              \
                }                                                               \
            }                                                                   \
        }                                                                       \
        __builtin_amdgcn_s_setprio(0);                                          \
        /* 5. my ds_reads retired, then refill the just-read buffer */          \
        asm volatile("s_waitcnt lgkmcnt(0)" ::: "memory");                      \
        {                                                                       \
            const int chd = ((N) + 2) & 63;                                     \
            const char* gsrc = Vgb + (size_t)chd * 32768 + l * 16;              \
            unsigned char* ldst = wlds + (BOFF) + l * 16;                       \
            _Pragma("unroll")                                                   \
            for (int i = 0; i < 4; ++i)                                         \
                __builtin_amdgcn_global_load_lds(                               \
                    (const __attribute__((address_space(1))) unsigned int*)(gsrc + i * 1024), \
                    (__attribute__((address_space(3))) unsigned int*)(ldst + i * 1024), \
                    16, 0, 0);                                                  \
        }                                                                       \
    }

    // ---- prologue: K(0) -> kf FIRST, then DMA(0)->buf0, DMA(1)->buf1 ----
    #pragma unroll
    for (int kh = 0; kh < 2; ++kh)
        kf[kh] = *(const short8*)(Kbb + (size_t)(32 * mh + l31) * CQK_
                                  + 16 * kh + 8 * h2);
    #pragma unroll
    for (int i = 0; i < 4; ++i)
        __builtin_amdgcn_global_load_lds(
            (const __attribute__((address_space(1))) unsigned int*)(Vgb + l * 16 + i * 1024),
            (__attribute__((address_space(3))) unsigned int*)(wlds + l * 16 + i * 1024),
            16, 0, 0);
    #pragma unroll
    for (int i = 0; i < 4; ++i)
        __builtin_amdgcn_global_load_lds(
            (const __attribute__((address_space(1))) unsigned int*)(Vgb + 32768 + l * 16 + i * 1024),
            (__attribute__((address_space(3))) unsigned int*)(wlds + 4096 + l * 16 + i * 1024),
            16, 0, 0);

    for (int mc = 0; mc < 64; mc += 2) {
        BODY(mc,     0)
        BODY(mc + 1, 4096)
    }
#undef BODY
#undef QK_JQ

    // ---- partial rowsums (own m-half): combine h2 halves, publish ----
    #pragma unroll
    for (int jq = 0; jq < 2; ++jq)
        rs[jq] += __shfl_xor(rs[jq], 32, 64);
    if (l < 32) {
        rstab[(w * 2 + 0) * 32 + l31] = rs[0];
        rstab[(w * 2 + 1) * 32 + l31] = rs[1];
    }
    __syncthreads();

    // ---- odd waves (mh=1): write partial acc into V-buffer area ----
    if (mh == 1) {
        float* dst = (float*)(smem + ch2 * 16384);
        #pragma unroll
        for (int jq = 0; jq < 2; ++jq)
            #pragma unroll
            for (int jc = 0; jc < 2; ++jc) {
                float* tb = dst + (jq * 2 + jc) * 1024 + l * 16;
                #pragma unroll
                for (int e4 = 0; e4 < 4; ++e4) {
                    f32x4 p;
                    p[0] = acc[jq][jc][4 * e4 + 0];
                    p[1] = acc[jq][jc][4 * e4 + 1];
                    p[2] = acc[jq][jc][4 * e4 + 2];
                    p[3] = acc[jq][jc][4 * e4 + 3];
                    *(f32x4*)(tb + 4 * (e4 ^ (l & 3))) = p;
                }
            }
    }
    __syncthreads();

    // ---- even waves (mh=0): combine + normalize + residual + store ----
    if (mh == 0) {
        const float* src = (const float*)(smem + ch2 * 16384);
        #pragma unroll
        for (int jq = 0; jq < 2; ++jq)
            #pragma unroll
            for (int jc = 0; jc < 2; ++jc) {
                const float* tb = src + (jq * 2 + jc) * 1024 + l * 16;
                #pragma unroll
                for (int e4 = 0; e4 < 4; ++e4) {
                    f32x4 p = *(const f32x4*)(tb + 4 * (e4 ^ (l & 3)));
                    acc[jq][jc][4 * e4 + 0] += p[0];
                    acc[jq][jc][4 * e4 + 1] += p[1];
                    acc[jq][jc][4 * e4 + 2] += p[2];
                    acc[jq][jc][4 * e4 + 3] += p[3];
                }
            }
        const float gm = gamma[0];
        #pragma unroll
        for (int jq = 0; jq < 2; ++jq)
            #pragma unroll
            for (int rg = 0; rg < 4; ++rg) {
                f32x4 s0 = *(const f32x4*)(rstab + (w * 2 + jq) * 32
                                           + 8 * rg + 4 * h2);
                f32x4 s1 = *(const f32x4*)(rstab + ((w + 1) * 2 + jq) * 32
                                           + 8 * rg + 4 * h2);
                float i0 = 1.0f / (s0[0] + s1[0]);
                float i1 = 1.0f / (s0[1] + s1[1]);
                float i2 = 1.0f / (s0[2] + s1[2]);
                float i3 = 1.0f / (s0[3] + s1[3]);
                const int n = n0 + 32 * jq + 8 * rg + 4 * h2;
                #pragma unroll
                for (int jc = 0; jc < 2; ++jc) {
                    const int c = 128 * cb + 64 * ch2 + 32 * jc + l31;
                    const size_t rowoff = (size_t)(b * C_ + c) * N_ + n;
                    float4 xv = *(const float4*)(x + rowoff);
                    float4 o;
                    o.x = gm * acc[jq][jc][4 * rg + 0] * i0 + xv.x;
                    o.y = gm * acc[jq][jc][4 * rg + 1] * i1 + xv.y;
                    o.z = gm * acc[jq][jc][4 * rg + 2] * i2 + xv.z;
                    o.w = gm * acc[jq][jc][4 * rg + 3] * i3 + xv.w;
                    *(float4*)(out + rowoff) = o;
                }
            }
    }
}

// ---------------------------------------------------------------------------
extern "C" void kernel_launch(void* const* d_in, const int* in_sizes, int n_in,
                              void* d_out, int out_size, void* d_ws, size_t ws_size,
                              hipStream_t stream)
{
    const float* x     = (const float*)d_in[0];
    const float* Wq    = (const float*)d_in[1];
    const float* bq    = (const float*)d_in[2];
    const float* Wk    = (const float*)d_in[3];
    const float* bk    = (const float*)d_in[4];
    const float* Wv    = (const float*)d_in[5];
    const float* bv    = (const float*)d_in[6];
    const float* gamma = (const float*)d_in[7];
    float* out = (float*)d_out;

    ushort_t* ws = (ushort_t*)d_ws;
    ushort_t* Qb   = ws;                                  // B*N*32 bf16
    ushort_t* Kb   = Qb + (size_t)B_ * N_ * CQK_;         // B*N*32 bf16
    ushort_t* Vt   = Kb + (size_t)B_ * N_ * CQK_;         // B*64 chunks * 32KB
    ushort_t* Wall = Vt + (size_t)B_ * C_ * N_;           // 320*256 bf16
    float*    ball = (float*)(Wall + (size_t)320 * C_);   // 320 f32

    prep_kernel<<<320, 256, 0, stream>>>(Wq, bq, Wk, bk, Wv, bv, Wall, ball);
    proj_kernel<<<B_ * (N_ / 64), 256, 0, stream>>>(x, Wall, ball, Qb, Kb, Vt);
    attn_kernel<<<B_ * (N_ / 64) * 2, 256, 0, stream>>>(x, Qb, Kb, Vt, gamma, out);
}

// Round 16
// 136.348 us; speedup vs baseline: 1.7994x; 1.2540x over previous
//
#include <hip/hip_runtime.h>

static constexpr int B_   = 8;
static constexpr int C_   = 256;
static constexpr int CQK_ = 32;
static constexpr int N_   = 4096;   // 64*64

typedef __attribute__((ext_vector_type(4)))  float f32x4;
typedef __attribute__((ext_vector_type(16))) float f32x16;
typedef __attribute__((ext_vector_type(8)))  short short8;
typedef __attribute__((ext_vector_type(2)))  unsigned int u32x2;
typedef unsigned short ushort_t;

// round-to-nearest-even fp32 -> bf16
__device__ inline unsigned short f2bf(float f) {
    unsigned u = __float_as_uint(f);
    return (unsigned short)((u + 0x7FFFu + ((u >> 16) & 1u)) >> 16);
}
__device__ inline unsigned packbf(float lo, float hi) {
    return (unsigned)f2bf(lo) | ((unsigned)f2bf(hi) << 16);
}
// packed f32->bf16 pair, single VOP3 (validated r6+)
__device__ inline unsigned cvtpk(float lo, float hi) {
    unsigned r;
    asm("v_cvt_pk_bf16_f32 %0, %1, %2" : "=v"(r) : "v"(lo), "v"(hi));
    return r;
}
// raw transcendental exp2 (input = log2-domain; Q pre-scaled by log2e)
__device__ inline float vexp2(float x) {
    float r;
    asm("v_exp_f32 %0, %1" : "=v"(r) : "v"(x));
    return r;
}
// v_permlane32_swap_b32 (validated r10)
__device__ inline void plswap(unsigned& a, unsigned& b) {
    asm("v_permlane32_swap_b32 %0, %1" : "+v"(a), "+v"(b));
}

// proj x-tile swizzle (validated r3-r15)
__device__ inline int swzbits(int m) {
    return ((m & 3) << 5) | (((m >> 3) & 1) << 4);
}

template <int OFF>
__device__ inline u32x2 tr8(unsigned a) {
    u32x2 d;
    asm volatile("ds_read_b64_tr_b16 %0, %1 offset:%2"
                 : "=v"(d) : "v"(a), "i"(OFF));
    return d;
}

__device__ inline short8 mk8(u32x2 lo, u32x2 hi) {
    union { unsigned u[4]; short8 s; } v;
    v.u[0] = lo.x; v.u[1] = lo.y; v.u[2] = hi.x; v.u[3] = hi.y;
    return v.s;
}
__device__ inline short8 mk8u(unsigned a, unsigned b, unsigned c, unsigned d) {
    union { unsigned u[4]; short8 s; } v;
    v.u[0] = a; v.u[1] = b; v.u[2] = c; v.u[3] = d;
    return v.s;
}

// ---------------------------------------------------------------------------
// prep: weights -> bf16 (Wq pre-scaled by log2e), biases -> f32
// ---------------------------------------------------------------------------
__global__ __launch_bounds__(256) void prep_kernel(
    const float* __restrict__ Wq, const float* __restrict__ bq,
    const float* __restrict__ Wk, const float* __restrict__ bk,
    const float* __restrict__ Wv, const float* __restrict__ bv,
    ushort_t* __restrict__ Wall, float* __restrict__ ball)
{
    const int r = blockIdx.x;
    const int t = threadIdx.x;
    const float LOG2E = 1.4426950408889634f;
    const float* src;
    float bsrc, sc;
    if (r < 32)      { src = Wq + (size_t)r * C_;        bsrc = bq[r];      sc = LOG2E; }
    else if (r < 64) { src = Wk + (size_t)(r - 32) * C_; bsrc = bk[r - 32]; sc = 1.0f; }
    else             { src = Wv + (size_t)(r - 64) * C_; bsrc = bv[r - 64]; sc = 1.0f; }
    Wall[(size_t)r * C_ + t] = f2bf(src[t] * sc);
    if (t == 0) ball[r] = bsrc * sc;
}

// ---------------------------------------------------------------------------
// Projection via MFMA (r12-r15 validated, incl. the V quadrant image:
//   byte = ((b*64+chunk)*4 + 2*ch + mh)*8192 + (c&127)*64
//        + 16*(((m&31)>>3) ^ (c&3) ^ ((c>>2)&3)) + 2*(m&7) )
// grid = 512 blocks (b = blk&7, XCD-affine), 256 threads (4 waves)
// ---------------------------------------------------------------------------
__global__ __launch_bounds__(256) void proj_kernel(
    const float* __restrict__ x,
    const ushort_t* __restrict__ Wall, const float* __restrict__ ball,
    ushort_t* __restrict__ Qb, ushort_t* __restrict__ Kb, ushort_t* __restrict__ Vt)
{
    __shared__ __align__(16) unsigned char xs[C_ * 128];   // 32 KB: [c][64n] bf16
    typedef __attribute__((address_space(3))) unsigned char lds_byte;
    const unsigned sbase = (unsigned)(size_t)(lds_byte*)xs;

    const int b  = blockIdx.x & 7;
    const int n0 = (blockIdx.x >> 3) << 6;
    const int t  = threadIdx.x;

    {
        const int cst = t >> 4;
        const int n4  = (t & 15) << 2;
        const float* xb = x + (size_t)b * C_ * N_ + n0;
        #pragma unroll
        for (int i = 0; i < 16; ++i) {
            const int c = 16 * i + cst;
            float4 v = *(const float4*)(xb + (size_t)c * N_ + n4);
            u32x2 pk;
            pk.x = packbf(v.x, v.y);
            pk.y = packbf(v.z, v.w);
            *(u32x2*)(xs + c * 128 + ((n4 * 2) ^ swzbits(c))) = pk;
        }
    }
    __syncthreads();

    const int l  = t & 63, w = t >> 6;
    const int li = l & 15, g = l >> 4;
    const int rr = li >> 2, ss = l & 3;
    const int swz_tr = (rr << 5) | ((g & 1) << 4);

    f32x4 acc[5][4];
    #pragma unroll
    for (int i = 0; i < 5; ++i)
        #pragma unroll
        for (int j = 0; j < 4; ++j) acc[i][j] = (f32x4){0.f, 0.f, 0.f, 0.f};

    #pragma unroll 2
    for (int kg = 0; kg < 8; ++kg) {
        u32x2 pb[4][2];
        #pragma unroll
        for (int jn = 0; jn < 4; ++jn) {
            unsigned a = sbase + (32 * kg + 8 * g + rr) * 128
                       + ((32 * jn + 8 * ss) ^ swz_tr);
            pb[jn][0] = tr8<0>(a);
            pb[jn][1] = tr8<512>(a);
        }
        short8 af[5];
        #pragma unroll
        for (int tm = 0; tm < 5; ++tm)
            af[tm] = *(const short8*)(Wall + (size_t)(16 * (4 * tm + w) + li) * C_
                                      + 32 * kg + 8 * g);
        asm volatile("s_waitcnt lgkmcnt(0)" ::: "memory");
        __builtin_amdgcn_sched_barrier(0);
        #pragma unroll
        for (int jn = 0; jn < 4; ++jn) {
            short8 Bf = mk8(pb[jn][0], pb[jn][1]);
            acc[0][jn] = __builtin_amdgcn_mfma_f32_16x16x32_bf16(
                             af[0], Bf, acc[0][jn], 0, 0, 0);
            #pragma unroll
            for (int tm = 1; tm < 5; ++tm)
                acc[tm][jn] = __builtin_amdgcn_mfma_f32_16x16x32_bf16(
                                  Bf, af[tm], acc[tm][jn], 0, 0, 0);
        }
    }

    // ---- epilogue: Q/K (unchanged, validated) ----
    {
        const int oc0 = 16 * w + 4 * g;
        float4 bias = *(const float4*)(ball + oc0);
        ushort_t* dst = (w < 2) ? Qb : Kb;
        const int col = (w < 2) ? oc0 : (oc0 - 32);
        #pragma unroll
        for (int jn = 0; jn < 4; ++jn) {
            const int n = n0 + 16 * jn + li;
            f32x4 a = acc[0][jn];
            u32x2 pk;
            pk.x = packbf(a[0] + bias.x, a[1] + bias.y);
            pk.y = packbf(a[2] + bias.z, a[3] + bias.w);
            *(u32x2*)(dst + (size_t)(b * N_ + n) * CQK_ + col) = pk;
        }
    }
    // ---- epilogue: V quadrant image (validated r12-r15) ----
    #pragma unroll
    for (int tm = 1; tm < 5; ++tm) {
        const int c  = 16 * (4 * tm + w) + li - 64;
        const float bc = ball[64 + c];
        const int ch = c >> 7;
        const int cl = c & 127;
        const int X  = (c & 3) ^ ((c >> 2) & 3);
        char* qbase = (char*)Vt + ((size_t)(b * 64 + (n0 >> 6)) * 4 + 2 * ch) * 8192
                    + cl * 64;
        #pragma unroll
        for (int jn = 0; jn < 4; ++jn) {
            const int mp = 16 * jn + 4 * g;
            const int mh = mp >> 5;
            const int jg = (mp & 31) >> 3;
            f32x4 a = acc[tm][jn];
            u32x2 pk;
            pk.x = packbf(a[0] + bc, a[1] + bc);
            pk.y = packbf(a[2] + bc, a[3] + bc);
            *(u32x2*)(qbase + mh * 8192 + 16 * (jg ^ X) + 8 * (g & 1)) = pk;
        }
    }
}

// ---------------------------------------------------------------------------
// Fused attention: 8-wave blocks (512 thr) at grid 512 -> 16 waves/CU.
// Wave (g = chunk parity, mh = m-half, ch2 = c-half): 32 chunks, 32m, 128c.
// Wave-private single-buffered 8KB V (DMA'd by the wave itself), in-register
// P (validated cvtpk+permlane), counted vmcnt only, barrier-free main loop.
// End: 4-partial (g x mh) combine via LDS (2 jq passes), then normalize.
// LDS: 8 x 8KB V + 2KB rstab = 67584 B -> 2 blocks/CU (grid-exact).
// ---------------------------------------------------------------------------
__global__ __launch_bounds__(512) void attn_kernel(
    const float* __restrict__ x,
    const ushort_t* __restrict__ Qb, const ushort_t* __restrict__ Kb,
    const ushort_t* __restrict__ Vt,
    const float* __restrict__ gamma, float* __restrict__ out)
{
    __shared__ __align__(16) unsigned char smem[67584];

    const int b   = blockIdx.x & 7;
    const int n0  = (blockIdx.x >> 3) << 6;
    const int t   = threadIdx.x;
    const int l   = t & 63, w = t >> 6;        // w in 0..7
    const int l31 = l & 31, h2 = l >> 5;
    const int g   = w & 1;                     // chunk parity
    const int mh  = (w >> 1) & 1;              // m-half within chunk
    const int ch2 = w >> 2;                    // c-half (128c)
    const int sxv = ((l31 & 3) ^ ((l31 >> 2) & 3)) << 4;
    unsigned char* wlds = smem + w * 8192;     // single 8KB private V buf
    float* rstab = (float*)(smem + 65536);     // [w][jq][32]

    // Q fragments (B-role: col = l31 -> q = n0+32jq+l31; k = 16kh+8h2+j)
    short8 qfv[2][2];
    #pragma unroll
    for (int jq = 0; jq < 2; ++jq)
        #pragma unroll
        for (int kh = 0; kh < 2; ++kh)
            qfv[jq][kh] = *(const short8*)(Qb
                + (size_t)(b * N_ + n0 + 32 * jq + l31) * CQK_ + 16 * kh + 8 * h2);

    f32x16 acc[2][4];
    #pragma unroll
    for (int i = 0; i < 2; ++i)
        #pragma unroll
        for (int j = 0; j < 4; ++j)
            #pragma unroll
            for (int e = 0; e < 16; ++e) acc[i][j][e] = 0.f;
    f32x16 zf16;
    #pragma unroll
    for (int e = 0; e < 16; ++e) zf16[e] = 0.f;
    float rs[2] = {0.f, 0.f};

    const ushort_t* Kbb = Kb + (size_t)(b * N_) * CQK_;
    const char* Vgb = (const char*)Vt + (size_t)b * 64 * 32768
                    + (2 * ch2 + mh) * 8192;   // my 8KB quadrant base

    short8 kf[2];

// QK for one jq of the chunk using kf; exp2; pack+permlane -> PAW
#define QK_JQ(JQ, PAW)                                                          \
    {                                                                           \
        f32x16 sv = __builtin_amdgcn_mfma_f32_32x32x16_bf16(                    \
                        kf[0], qfv[JQ][0], zf16, 0, 0, 0);                      \
        sv = __builtin_amdgcn_mfma_f32_32x32x16_bf16(                           \
                 kf[1], qfv[JQ][1], sv, 0, 0, 0);                               \
        _Pragma("unroll")                                                       \
        for (int s = 0; s < 2; ++s) {                                           \
            float e0 = vexp2(sv[8*s+0]), e1 = vexp2(sv[8*s+1]);                 \
            float e2 = vexp2(sv[8*s+2]), e3 = vexp2(sv[8*s+3]);                 \
            float e4 = vexp2(sv[8*s+4]), e5 = vexp2(sv[8*s+5]);                 \
            float e6 = vexp2(sv[8*s+6]), e7 = vexp2(sv[8*s+7]);                 \
            rs[JQ] += ((e0 + e1) + (e2 + e3)) + ((e4 + e5) + (e6 + e7));        \
            unsigned u0 = cvtpk(e0, e1), u1 = cvtpk(e2, e3);                    \
            unsigned u2 = cvtpk(e4, e5), u3 = cvtpk(e6, e7);                    \
            plswap(u0, u2); plswap(u1, u3);                                     \
            PAW[JQ][s][0] = u0; PAW[JQ][s][1] = u1;                             \
            PAW[JQ][s][2] = u2; PAW[JQ][s][3] = u3;                             \
        }                                                                       \
    }

    // ---- prologue: K(chunk g) -> kf FIRST, then DMA(chunk g) -> buf ----
    #pragma unroll
    for (int kh = 0; kh < 2; ++kh)
        kf[kh] = *(const short8*)(Kbb + (size_t)(64 * g + 32 * mh + l31) * CQK_
                                  + 16 * kh + 8 * h2);
    #pragma unroll
    for (int i = 0; i < 8; ++i)
        __builtin_amdgcn_global_load_lds(
            (const __attribute__((address_space(1))) unsigned int*)
                (Vgb + (size_t)g * 32768 + l * 16 + i * 1024),
            (__attribute__((address_space(3))) unsigned int*)(wlds + l * 16 + i * 1024),
            16, 0, 0);

    // ---- main loop: 32 chunks of my parity, barrier-free ----
    for (int i = 0; i < 32; ++i) {
        const int n = g + 2 * i;
        // 1. QK(n): implicit kf-wait is vmcnt(8) (kf older than DMA(n)) ->
        //    DMA(n)'s 8 loads stay in flight under the QK+exp chain
        unsigned paw[2][2][4];
        QK_JQ(0, paw)
        QK_JQ(1, paw)
        // 2. K(n+2) -> kf (regs freed by QK)
        {
            const int chk = (n + 2) & 63;
            #pragma unroll
            for (int kh = 0; kh < 2; ++kh)
                kf[kh] = *(const short8*)(Kbb
                    + (size_t)(64 * chk + 32 * mh + l31) * CQK_ + 16 * kh + 8 * h2);
        }
        // 3. DMA(n) retired; kf(n+2)=2 stays in flight
        asm volatile("s_waitcnt vmcnt(2)" ::: "memory");
        // 4. PV(n): A = register P, B = my V quadrant (b128, swizzled)
        __builtin_amdgcn_s_setprio(1);
        #pragma unroll
        for (int s = 0; s < 2; ++s) {
            short8 A0 = mk8u(paw[0][s][0], paw[0][s][1], paw[0][s][2], paw[0][s][3]);
            short8 A1 = mk8u(paw[1][s][0], paw[1][s][1], paw[1][s][2], paw[1][s][3]);
            #pragma unroll
            for (int jc = 0; jc < 4; ++jc) {
                short8 vv = *(const short8*)(wlds + (32 * jc + l31) * 64
                               + ((32 * s + 16 * h2) ^ sxv));
                acc[0][jc] = __builtin_amdgcn_mfma_f32_32x32x16_bf16(
                                 A0, vv, acc[0][jc], 0, 0, 0);
                acc[1][jc] = __builtin_amdgcn_mfma_f32_32x32x16_bf16(
                                 A1, vv, acc[1][jc], 0, 0, 0);
            }
        }
        __builtin_amdgcn_s_setprio(0);
        // 5. my ds_reads retired, then refill my buffer with chunk n+2
        asm volatile("s_waitcnt lgkmcnt(0)" ::: "memory");
        {
            const int chd = (n + 2) & 63;
            const char* gsrc = Vgb + (size_t)chd * 32768 + l * 16;
            #pragma unroll
            for (int i2 = 0; i2 < 8; ++i2)
                __builtin_amdgcn_global_load_lds(
                    (const __attribute__((address_space(1))) unsigned int*)(gsrc + i2 * 1024),
                    (__attribute__((address_space(3))) unsigned int*)(wlds + l * 16 + i2 * 1024),
                    16, 0, 0);
        }
    }
#undef QK_JQ

    // drain wrap-around DMA before reusing the V area for the combine
    asm volatile("s_waitcnt vmcnt(0)" ::: "memory");

    // ---- partial rowsums: fold h2, publish per wave ----
    #pragma unroll
    for (int jq = 0; jq < 2; ++jq)
        rs[jq] += __shfl_xor(rs[jq], 32, 64);
    if (l < 32) {
        rstab[w * 64 + l31]      = rs[0];
        rstab[w * 64 + 32 + l31] = rs[1];
    }

    // ---- combine over (g, mh): 2 passes (jq), 4 syncs each ----
    const float gm = gamma[0];
    #pragma unroll
    for (int jq = 0; jq < 2; ++jq) {
        __syncthreads();
        if (g == 1) {                          // stage 1: g=1 waves publish
            float* tb = (float*)(smem + (2 * mh + ch2) * 16384);
            #pragma unroll
            for (int jc = 0; jc < 4; ++jc)
                #pragma unroll
                for (int e4 = 0; e4 < 4; ++e4) {
                    f32x4 p;
                    p[0] = acc[jq][jc][4 * e4 + 0];
                    p[1] = acc[jq][jc][4 * e4 + 1];
                    p[2] = acc[jq][jc][4 * e4 + 2];
                    p[3] = acc[jq][jc][4 * e4 + 3];
                    *(f32x4*)(tb + jc * 1024 + l * 16 + 4 * (e4 ^ (l & 3))) = p;
                }
        }
        __syncthreads();
        if (g == 0) {                          // g=0 waves absorb parity partner
            const float* tb = (const float*)(smem + (2 * mh + ch2) * 16384);
            #pragma unroll
            for (int jc = 0; jc < 4; ++jc)
                #pragma unroll
                for (int e4 = 0; e4 < 4; ++e4) {
                    f32x4 p = *(const f32x4*)(tb + jc * 1024 + l * 16 + 4 * (e4 ^ (l & 3)));
                    acc[jq][jc][4 * e4 + 0] += p[0];
                    acc[jq][jc][4 * e4 + 1] += p[1];
                    acc[jq][jc][4 * e4 + 2] += p[2];
                    acc[jq][jc][4 * e4 + 3] += p[3];
                }
        }
        __syncthreads();
        if (g == 0 && mh == 1) {               // stage 2: mh=1 publishes merged
            float* tb = (float*)(smem + ch2 * 16384);
            #pragma unroll
            for (int jc = 0; jc < 4; ++jc)
                #pragma unroll
                for (int e4 = 0; e4 < 4; ++e4) {
                    f32x4 p;
                    p[0] = acc[jq][jc][4 * e4 + 0];
                    p[1] = acc[jq][jc][4 * e4 + 1];
                    p[2] = acc[jq][jc][4 * e4 + 2];
                    p[3] = acc[jq][jc][4 * e4 + 3];
                    *(f32x4*)(tb + jc * 1024 + l * 16 + 4 * (e4 ^ (l & 3))) = p;
                }
        }
        __syncthreads();
        if (g == 0 && mh == 0) {               // final: sum, normalize, store
            const float* tb = (const float*)(smem + ch2 * 16384);
            #pragma unroll
            for (int jc = 0; jc < 4; ++jc)
                #pragma unroll
                for (int e4 = 0; e4 < 4; ++e4) {
                    f32x4 p = *(const f32x4*)(tb + jc * 1024 + l * 16 + 4 * (e4 ^ (l & 3)));
                    acc[jq][jc][4 * e4 + 0] += p[0];
                    acc[jq][jc][4 * e4 + 1] += p[1];
                    acc[jq][jc][4 * e4 + 2] += p[2];
                    acc[jq][jc][4 * e4 + 3] += p[3];
                }
            #pragma unroll
            for (int rg = 0; rg < 4; ++rg) {
                const int ro = 32 * jq + 8 * rg + 4 * h2;
                f32x4 s0 = *(const f32x4*)(rstab + (4 * ch2 + 0) * 64 + ro);
                f32x4 s1 = *(const f32x4*)(rstab + (4 * ch2 + 1) * 64 + ro);
                f32x4 s2 = *(const f32x4*)(rstab + (4 * ch2 + 2) * 64 + ro);
                f32x4 s3 = *(const f32x4*)(rstab + (4 * ch2 + 3) * 64 + ro);
                f32x4 sm = (s0 + s1) + (s2 + s3);
                float i0 = 1.0f / sm[0], i1 = 1.0f / sm[1];
                float i2 = 1.0f / sm[2], i3 = 1.0f / sm[3];
                const int n = n0 + 32 * jq + 8 * rg + 4 * h2;
                #pragma unroll
                for (int jc = 0; jc < 4; ++jc) {
                    const int c = 128 * ch2 + 32 * jc + l31;
                    const size_t rowoff = (size_t)(b * C_ + c) * N_ + n;
                    float4 xv = *(const float4*)(x + rowoff);
                    float4 o;
                    o.x = gm * acc[jq][jc][4 * rg + 0] * i0 + xv.x;
                    o.y = gm * acc[jq][jc][4 * rg + 1] * i1 + xv.y;
                    o.z = gm * acc[jq][jc][4 * rg + 2] * i2 + xv.z;
                    o.w = gm * acc[jq][jc][4 * rg + 3] * i3 + xv.w;
                    *(float4*)(out + rowoff) = o;
                }
            }
        }
    }
}

// ---------------------------------------------------------------------------
extern "C" void kernel_launch(void* const* d_in, const int* in_sizes, int n_in,
                              void* d_out, int out_size, void* d_ws, size_t ws_size,
                              hipStream_t stream)
{
    const float* x     = (const float*)d_in[0];
    const float* Wq    = (const float*)d_in[1];
    const float* bq    = (const float*)d_in[2];
    const float* Wk    = (const float*)d_in[3];
    const float* bk    = (const float*)d_in[4];
    const float* Wv    = (const float*)d_in[5];
    const float* bv    = (const float*)d_in[6];
    const float* gamma = (const float*)d_in[7];
    float* out = (float*)d_out;

    ushort_t* ws = (ushort_t*)d_ws;
    ushort_t* Qb   = ws;                                  // B*N*32 bf16
    ushort_t* Kb   = Qb + (size_t)B_ * N_ * CQK_;         // B*N*32 bf16
    ushort_t* Vt   = Kb + (size_t)B_ * N_ * CQK_;         // B*64 chunks * 32KB
    ushort_t* Wall = Vt + (size_t)B_ * C_ * N_;           // 320*256 bf16
    float*    ball = (float*)(Wall + (size_t)320 * C_);   // 320 f32

    prep_kernel<<<320, 256, 0, stream>>>(Wq, bq, Wk, bk, Wv, bv, Wall, ball);
    proj_kernel<<<B_ * (N_ / 64), 256, 0, stream>>>(x, Wall, ball, Qb, Kb, Vt);
    attn_kernel<<<B_ * (N_ / 64), 512, 0, stream>>>(x, Qb, Kb, Vt, gamma, out);
}